// Round 5
// baseline (57.541 us; speedup 1.0000x reference)
//
#include <hip/hip_runtime.h>
#include <hip/hip_bf16.h>

#define DD 256
#define SS 4096

typedef __bf16 bf16x8 __attribute__((ext_vector_type(8)));
typedef float  f32x4  __attribute__((ext_vector_type(4)));

__device__ __forceinline__ float fast_tanh(float x) {
  float e = __expf(2.0f * x);
  return 1.0f - 2.0f / (e + 1.0f);
}

// DPP helpers: reduce across the 16-lane row (lg = lane&15) within each g-group
template<int CTRL>
__device__ __forceinline__ float dpp_mov(float v) {
  return __int_as_float(__builtin_amdgcn_update_dpp(0, __float_as_int(v), CTRL, 0xF, 0xF, true));
}
__device__ __forceinline__ float row16_sum(float v) {
  v += dpp_mov<0xB1>(v);   // quad_perm xor1
  v += dpp_mov<0x4E>(v);   // quad_perm xor2
  v += dpp_mov<0x124>(v);  // row_ror:4
  v += dpp_mov<0x128>(v);  // row_ror:8
  return v;
}
__device__ __forceinline__ float row16_max(float v) {
  v = fmaxf(v, dpp_mov<0xB1>(v));
  v = fmaxf(v, dpp_mov<0x4E>(v));
  v = fmaxf(v, dpp_mov<0x124>(v));
  v = fmaxf(v, dpp_mov<0x128>(v));
  return v;
}

// Prep: W [256,256] fp32 -> fragment-ordered bf16 WF.
// Chunk c = ((n0*8+ks)*64 + lane) holds 8 bf16: W[ks*32+(lane>>4)*8+i][n0*16+(lane&15)]
__global__ __launch_bounds__(256) void prep_kernel(
    const float* __restrict__ W, __bf16* __restrict__ WF)
{
  const int c = blockIdx.x * 256 + threadIdx.x;   // 8192 chunks
  const int lane_c = c & 63;
  const int ks  = (c >> 6) & 7;
  const int n0  = c >> 9;
  const int col = n0 * 16 + (lane_c & 15);
  const int k0  = ks * 32 + (lane_c >> 4) * 8;
  const float* wp = W + k0 * DD + col;
  bf16x8 fr;
  #pragma unroll
  for (int i = 0; i < 8; ++i) fr[i] = (__bf16)wp[i * DD];
  *reinterpret_cast<bf16x8*>(WF + (size_t)c * 8) = fr;
}

#define LOADB(buf, n0q) { \
  const bf16x8* _src = WFv + ((n0q) * 8 * 64 + lane); \
  _Pragma("unroll") \
  for (int _ks = 0; _ks < 8; ++_ks) buf[_ks] = _src[_ks * 64]; }

#define COMPUTE(buf, n0q) { \
  f32x4 _acc0 = {0.f,0.f,0.f,0.f}; \
  f32x4 _acc1 = {0.f,0.f,0.f,0.f}; \
  _Pragma("unroll") \
  for (int _ks = 0; _ks < 8; ++_ks) { \
    _acc0 = __builtin_amdgcn_mfma_f32_16x16x32_bf16(a[0][_ks], buf[_ks], _acc0, 0, 0, 0); \
    _acc1 = __builtin_amdgcn_mfma_f32_16x16x32_bf16(a[1][_ks], buf[_ks], _acc1, 0, 0, 0); } \
  const int _col = (n0q) * 16 + lg; \
  const float _vc = Vs[_col], _bc = Bs[_col]; \
  _Pragma("unroll") \
  for (int _r = 0; _r < 4; ++_r) { \
    sp0[_r] += fast_tanh(_acc0[_r] + _bc) * _vc; \
    sp1[_r] += fast_tanh(_acc1[_r] + _bc) * _vc; } }

// Fused kernel: per block (256 rows = 1/16 of a batch):
//   logits = tanh(x@W+b)@V  (MFMA, x rows in registers; W-frags from L2)
//   block-local softmax: M_blk, S_blk, P_blk[256] = sum_s exp(l_s-M_blk)*x_s
// X read from HBM exactly once. 512 threads, ~10 KB LDS -> 2+ blocks/CU.
__global__ __launch_bounds__(512, 4) void fused_kernel(
    const float* __restrict__ X, const __bf16* __restrict__ WF,
    const float* __restrict__ bias, const float* __restrict__ V,
    float* __restrict__ Pout, float* __restrict__ Mout, float* __restrict__ Sout)
{
  __shared__ float Pacc[8][DD];   // 8 KB
  __shared__ float Vs[DD];
  __shared__ float Bs[DD];
  __shared__ float wred[8];
  __shared__ float sred[8];

  const int t = threadIdx.x;
  if (t < DD) { Vs[t] = V[t]; Bs[t] = bias[t]; }
  __syncthreads();

  const int wave = t >> 6, lane = t & 63;
  const int g  = lane >> 4;   // k-group 0..3 (DPP row)
  const int lg = lane & 15;   // sub-lane 0..15
  const size_t rowBase = (size_t)blockIdx.x * 256 + (size_t)wave * 32;
  const bf16x8* WFv = reinterpret_cast<const bf16x8*>(WF);

  // ---- Phase 1: load A fragments (the only HBM read of X) ----
  bf16x8 a[2][8];   // [strip][k-step]; lane holds row st*16+lg, k = ks*32+g*8+i
  #pragma unroll
  for (int st = 0; st < 2; ++st) {
    const float* xr = X + (rowBase + st * 16 + lg) * DD;
    #pragma unroll
    for (int ks = 0; ks < 8; ++ks) {
      const float4* p = reinterpret_cast<const float4*>(xr + ks * 32 + g * 8);
      float4 f0 = p[0], f1 = p[1];
      bf16x8 fr;
      fr[0] = (__bf16)f0.x; fr[1] = (__bf16)f0.y; fr[2] = (__bf16)f0.z; fr[3] = (__bf16)f0.w;
      fr[4] = (__bf16)f1.x; fr[5] = (__bf16)f1.y; fr[6] = (__bf16)f1.z; fr[7] = (__bf16)f1.w;
      a[st][ks] = fr;
    }
  }

  // ---- Phase 2: 16 col-tiles; B-frags from L2, register double-buffered ----
  float sp0[4] = {0.f,0.f,0.f,0.f};
  float sp1[4] = {0.f,0.f,0.f,0.f};
  bf16x8 bufA[8], bufB[8];
  LOADB(bufA, 0);
  #pragma unroll
  for (int n2 = 0; n2 < 8; ++n2) {
    LOADB(bufB, n2 * 2 + 1);
    COMPUTE(bufA, n2 * 2);
    if (n2 < 7) LOADB(bufA, n2 * 2 + 2);
    COMPUTE(bufB, n2 * 2 + 1);
  }

  // Reduce logit partials across the 16 lg-lanes (DPP, all lanes get the sum)
  #pragma unroll
  for (int r = 0; r < 4; ++r) { sp0[r] = row16_sum(sp0[r]); sp1[r] = row16_sum(sp1[r]); }

  // Group g holds logits of rows g*4+r (strip0) / 16+g*4+r (strip1), all lg.
  // Redistribute: lane (g,lg) needs rows lg and 16+lg -> src group lg>>2, elem lg&3.
  const int src = ((lg >> 2) << 4) | lg;
  float l0 = 0.f, l1 = 0.f;
  #pragma unroll
  for (int r = 0; r < 4; ++r) {
    float v0 = __shfl(sp0[r], src, 64);
    float v1 = __shfl(sp1[r], src, 64);
    if ((lg & 3) == r) { l0 = v0; l1 = v1; }
  }

  // ---- Phase 3: block-local softmax numerators ----
  float wm = row16_max(fmaxf(l0, l1));   // l0,l1 depend only on lg
  if (lane == 0) wred[wave] = wm;
  __syncthreads();
  float M = -1e30f;
  #pragma unroll
  for (int w = 0; w < 8; ++w) M = fmaxf(M, wred[w]);

  const float w0 = __expf(l0 - M);
  const float w1 = __expf(l1 - M);

  float se = row16_sum(w0 + w1);
  if (lane == 0) sred[wave] = se;

  // Weighted partial sums: p8[i] covers d = ks*32+g*8+i; DPP row-reduce over lg.
  #pragma unroll
  for (int ks = 0; ks < 8; ++ks) {
    float p8[8];
    #pragma unroll
    for (int i = 0; i < 8; ++i)
      p8[i] = w0 * (float)a[0][ks][i] + w1 * (float)a[1][ks][i];
    #pragma unroll
    for (int i = 0; i < 8; ++i) p8[i] = row16_sum(p8[i]);
    if (lg < 2) {
      float4 v = (lg == 0) ? make_float4(p8[0], p8[1], p8[2], p8[3])
                           : make_float4(p8[4], p8[5], p8[6], p8[7]);
      *reinterpret_cast<float4*>(&Pacc[wave][ks * 32 + g * 8 + lg * 4]) = v;
    }
  }
  __syncthreads();

  // ---- Phase 4: cross-wave reduce + write per-block partials ----
  if (t < DD) {
    float s = 0.f;
    #pragma unroll
    for (int w = 0; w < 8; ++w) s += Pacc[w][t];
    Pout[(size_t)blockIdx.x * DD + t] = s;
  }
  if (t == 0) {
    float ss = 0.f;
    #pragma unroll
    for (int w = 0; w < 8; ++w) ss += sred[w];
    Sout[blockIdx.x] = ss;
    Mout[blockIdx.x] = M;
  }
}

// Combine: per batch, merge the 16 chunk partials with max-rescale.
__global__ __launch_bounds__(256) void combine_kernel(
    const float* __restrict__ P, const float* __restrict__ Mb,
    const float* __restrict__ Sb, float* __restrict__ ctx)
{
  const int b = blockIdx.x, t = threadIdx.x;
  float Mg = -1e30f;
  #pragma unroll
  for (int k = 0; k < 16; ++k) Mg = fmaxf(Mg, Mb[b * 16 + k]);
  float denom = 0.f, acc = 0.f;
  #pragma unroll
  for (int k = 0; k < 16; ++k) {
    const float f = __expf(Mb[b * 16 + k] - Mg);
    denom += f * Sb[b * 16 + k];
    acc   += f * P[(size_t)(b * 16 + k) * DD + t];
  }
  ctx[b * DD + t] = acc / denom;
}

extern "C" void kernel_launch(void* const* d_in, const int* in_sizes, int n_in,
                              void* d_out, int out_size, void* d_ws, size_t ws_size,
                              hipStream_t stream) {
  const float* X    = (const float*)d_in[0];  // [32,4096,256] fp32
  const float* W    = (const float*)d_in[1];  // [256,256]
  const float* bias = (const float*)d_in[2];  // [256]
  const float* V    = (const float*)d_in[3];  // [256,1]
  float* ctx = (float*)d_out;                 // [32,256]

  __bf16* WF = (__bf16*)d_ws;                 // 65536 bf16 = 128 KB, fragment-ordered
  float* P = (float*)((char*)d_ws + 128 * 1024);  // [512,256] = 512 KB
  float* M = P + 512 * DD;                    // [512]
  float* S = M + 512;                         // [512]

  prep_kernel<<<32, 256, 0, stream>>>(W, WF);
  fused_kernel<<<512, 512, 0, stream>>>(X, WF, bias, V, P, M, S);
  combine_kernel<<<32, 256, 0, stream>>>(P, M, S, ctx);
}